// Round 1
// baseline (60.878 us; speedup 1.0000x reference)
//
#include <hip/hip_runtime.h>

// UVFA_text: B=256, M=10 (M2=100), SV=OV=32, R=128, L=12, V=1000, E=64
// out[b,p] = h2(b,p) . u[b] + bs3.w[b]
//   h2 = relu( relu(base_s[b] + Ws1_pos[p]) @ Ws2 + bs2 )
//   base_s[b] = bs1 + sum_c Ws1[c*33+state[b,c]]
//   w[b] = obj_mlp(b) * lstm_h(b);  u[b] = Ws3 @ w[b]

#define B_   256
#define M2_  100
#define SV_  32
#define OV_  32
#define R_   128
#define L_   12
#define E_   64
#define G4_  512   // 4*R

__device__ __forceinline__ float sigf(float x) { return 1.f / (1.f + expf(-x)); }

__global__ __launch_bounds__(512, 2) void uvfa_kernel(
    const int* __restrict__ state, const int* __restrict__ obj, const int* __restrict__ text,
    const float* __restrict__ Ws1, const float* __restrict__ bs1,
    const float* __restrict__ Ws2, const float* __restrict__ bs2,
    const float* __restrict__ Ws3, const float* __restrict__ bs3,
    const float* __restrict__ Wo1, const float* __restrict__ bo1,
    const float* __restrict__ Wo2, const float* __restrict__ bo2,
    const float* __restrict__ Wo3, const float* __restrict__ bo3,
    const float* __restrict__ emb, const float* __restrict__ Wih,
    const float* __restrict__ Whh, const float* __restrict__ b_lstm,
    float* __restrict__ out)
{
    const int b   = blockIdx.x;
    const int tid = threadIdx.x;
    const int k   = tid & 127;   // 0..127
    const int q   = tid >> 7;    // 0..3

    __shared__ float xw[L_][G4_];     // 24 KB: precomputed x_t@Wih + b
    __shared__ float xemb[L_ * E_];   // 3 KB : embedded text
    __shared__ int   tids[L_];
    __shared__ int   idx[M2_];
    __shared__ float hbuf[R_];
    __shared__ float gbuf[G4_];
    __shared__ float part[4 * R_];
    __shared__ float tmp[R_];
    __shared__ float tmp2[R_];
    __shared__ float wbuf[R_];
    __shared__ float ubuf[R_];
    __shared__ float bsbuf[R_];
    __shared__ float h1s[4][R_];
    __shared__ float red[4][2];
    __shared__ float c0s;

    // ---------- text ids + embedding rows into LDS ----------
    if (tid < L_) tids[tid] = text[b * L_ + tid];
    if (tid < R_) hbuf[tid] = 0.f;
    __syncthreads();
    for (int i = tid; i < L_ * E_; i += G4_) {
        int t = i >> 6, e = i & 63;
        xemb[i] = emb[tids[t] * E_ + e];
    }
    __syncthreads();

    // ---------- xw[t][col] = b_lstm[col] + sum_e xemb[t][e]*Wih[e][col] ----------
    {
        float acc[L_];
        float bl = b_lstm[tid];
        #pragma unroll
        for (int t = 0; t < L_; ++t) acc[t] = bl;
        for (int e = 0; e < E_; ++e) {
            float we = Wih[e * G4_ + tid];       // coalesced across 512 threads
            #pragma unroll
            for (int t = 0; t < L_; ++t) acc[t] = fmaf(xemb[t * E_ + e], we, acc[t]);
        }
        #pragma unroll
        for (int t = 0; t < L_; ++t) xw[t][tid] = acc[t];
    }

    // ---------- Whh column (thread = gate column) register-resident ----------
    float wcol[R_];
    #pragma unroll
    for (int kk = 0; kk < R_; ++kk) wcol[kk] = Whh[kk * G4_ + tid];
    __syncthreads();

    // ---------- LSTM recurrence, 12 steps ----------
    float cst = 0.f;
    for (int t = 0; t < L_; ++t) {
        float g = xw[t][tid];
        #pragma unroll
        for (int kk = 0; kk < R_; ++kk) g = fmaf(hbuf[kk], wcol[kk], g);  // hbuf: LDS broadcast
        gbuf[tid] = g;
        __syncthreads();
        if (tid < R_) {
            float gi = gbuf[tid], gf = gbuf[R_ + tid], gg = gbuf[2 * R_ + tid], go = gbuf[3 * R_ + tid];
            cst = sigf(gf) * cst + sigf(gi) * tanhf(gg);
            hbuf[tid] = sigf(go) * tanhf(cst);
        }
        __syncthreads();
    }
    // hbuf now = final lstm hidden (128)

    // ---------- object MLP (one row per b; layer1 = gather-sum of Wo1 rows) ----------
    if (tid < M2_) idx[tid] = obj[b * M2_ + tid];
    __syncthreads();
    {
        float acc = 0.f;
        #pragma unroll 5
        for (int c = q * 25; c < q * 25 + 25; ++c)
            acc += Wo1[(c * OV_ + idx[c]) * R_ + k];       // coalesced 512B rows
        part[q * R_ + k] = acc;
    }
    __syncthreads();
    if (tid < R_) tmp[tid] = fmaxf(bo1[tid] + part[tid] + part[R_ + tid] + part[2 * R_ + tid] + part[3 * R_ + tid], 0.f);
    __syncthreads();
    {
        float acc = 0.f;
        #pragma unroll 8
        for (int kk = q * 32; kk < q * 32 + 32; ++kk)
            acc = fmaf(tmp[kk], Wo2[kk * R_ + k], acc);
        part[q * R_ + k] = acc;
    }
    __syncthreads();
    if (tid < R_) tmp2[tid] = fmaxf(bo2[tid] + part[tid] + part[R_ + tid] + part[2 * R_ + tid] + part[3 * R_ + tid], 0.f);
    __syncthreads();
    {
        float acc = 0.f;
        #pragma unroll 8
        for (int kk = q * 32; kk < q * 32 + 32; ++kk)
            acc = fmaf(tmp2[kk], Wo3[kk * R_ + k], acc);
        part[q * R_ + k] = acc;
    }
    __syncthreads();
    if (tid < R_)
        wbuf[tid] = (bo3[tid] + part[tid] + part[R_ + tid] + part[2 * R_ + tid] + part[3 * R_ + tid]) * hbuf[tid];
    __syncthreads();

    // ---------- u[k] = sum_j Ws3[k][j]*w[j] ; c0 = bs3 . w ----------
    {
        float acc = 0.f;
        const float4* w4 = reinterpret_cast<const float4*>(&Ws3[k * R_ + q * 32]);
        #pragma unroll
        for (int jj = 0; jj < 8; ++jj) {
            float4 v = w4[jj];
            int j0 = q * 32 + jj * 4;
            acc = fmaf(v.x, wbuf[j0 + 0], acc);
            acc = fmaf(v.y, wbuf[j0 + 1], acc);
            acc = fmaf(v.z, wbuf[j0 + 2], acc);
            acc = fmaf(v.w, wbuf[j0 + 3], acc);
        }
        part[q * R_ + k] = acc;
    }
    __syncthreads();
    if (tid < R_) ubuf[tid] = part[tid] + part[R_ + tid] + part[2 * R_ + tid] + part[3 * R_ + tid];
    if (tid == G4_ - 1) {
        float s = 0.f;
        for (int j = 0; j < R_; ++j) s += bs3[j] * wbuf[j];
        c0s = s;
    }
    __syncthreads();

    // ---------- base_s[b] = bs1 + sum_c Ws1[c*33+state[b,c]] ----------
    if (tid < M2_) idx[tid] = state[b * M2_ + tid];
    __syncthreads();
    {
        float acc = 0.f;
        #pragma unroll 5
        for (int c = q * 25; c < q * 25 + 25; ++c)
            acc += Ws1[(c * 33 + idx[c]) * R_ + k];
        part[q * R_ + k] = acc;
    }
    __syncthreads();
    if (tid < R_) bsbuf[tid] = bs1[tid] + part[tid] + part[R_ + tid] + part[2 * R_ + tid] + part[3 * R_ + tid];

    // ---------- Ws2 column register-resident (reuse wcol) ----------
    #pragma unroll
    for (int kk = 0; kk < R_; ++kk) wcol[kk] = Ws2[kk * R_ + k];
    __syncthreads();

    const int   pl   = q;          // 4 positions per iteration
    const float ubk  = ubuf[k];
    const float c0v  = c0s;
    const float bsk  = bsbuf[k];
    const float bs2k = bs2[k];

    // ---------- main loop: 100 positions, 4 at a time ----------
    for (int p0 = 0; p0 < M2_; p0 += 4) {
        int p = p0 + pl;
        h1s[pl][k] = fmaxf(bsk + Ws1[(p * 33 + 32) * R_ + k], 0.f);
        __syncthreads();
        float acc = bs2k;
        #pragma unroll
        for (int j = 0; j < R_; j += 4) {
            float4 h4 = *reinterpret_cast<const float4*>(&h1s[pl][j]);  // LDS b128 broadcast
            acc = fmaf(h4.x, wcol[j + 0], acc);
            acc = fmaf(h4.y, wcol[j + 1], acc);
            acc = fmaf(h4.z, wcol[j + 2], acc);
            acc = fmaf(h4.w, wcol[j + 3], acc);
        }
        float val = fmaxf(acc, 0.f) * ubk;
        #pragma unroll
        for (int off = 32; off > 0; off >>= 1) val += __shfl_down(val, off, 64);
        if ((tid & 63) == 0) red[pl][(tid >> 6) & 1] = val;
        __syncthreads();
        if (k == 0) out[b * M2_ + p] = red[pl][0] + red[pl][1] + c0v;
        // safe to overwrite h1s next iter: all reads completed before the barrier above
    }
}

extern "C" void kernel_launch(void* const* d_in, const int* in_sizes, int n_in,
                              void* d_out, int out_size, void* d_ws, size_t ws_size,
                              hipStream_t stream) {
    const int*   state  = (const int*)d_in[0];
    const int*   obj    = (const int*)d_in[1];
    const int*   text   = (const int*)d_in[2];
    const float* Ws1    = (const float*)d_in[3];
    const float* bs1    = (const float*)d_in[4];
    const float* Ws2    = (const float*)d_in[5];
    const float* bs2    = (const float*)d_in[6];
    const float* Ws3    = (const float*)d_in[7];
    const float* bs3    = (const float*)d_in[8];
    const float* Wo1    = (const float*)d_in[9];
    const float* bo1    = (const float*)d_in[10];
    const float* Wo2    = (const float*)d_in[11];
    const float* bo2    = (const float*)d_in[12];
    const float* Wo3    = (const float*)d_in[13];
    const float* bo3    = (const float*)d_in[14];
    const float* emb    = (const float*)d_in[15];
    const float* Wih    = (const float*)d_in[16];
    const float* Whh    = (const float*)d_in[17];
    const float* b_lstm = (const float*)d_in[18];
    float* out = (float*)d_out;

    hipLaunchKernelGGL(uvfa_kernel, dim3(B_), dim3(G4_), 0, stream,
                       state, obj, text, Ws1, bs1, Ws2, bs2, Ws3, bs3,
                       Wo1, bo1, Wo2, bo2, Wo3, bo3, emb, Wih, Whh, b_lstm, out);
}